// Round 11
// baseline (1483.742 us; speedup 1.0000x reference)
//
#include <hip/hip_runtime.h>
#include <hip/hip_bf16.h>
#include <hip/hip_fp16.h>

#define N_NODES 50000
#define MPAD    50048            // 391 * 128
#define NRB     391              // MPAD/128 row-blocks
#define N_EDGES 800000
#define IN_DIM  128
#define HID     256
#define QKVW    768              // q | k | v concatenated row
#define N_LAYERS 8
#define OUT_DIM 40
#define SCALING 0.17677669529663687f

typedef __attribute__((ext_vector_type(8))) _Float16 f16x8;
typedef __attribute__((ext_vector_type(4))) float f32x4;

__device__ __forceinline__ void gload_lds16(const void* g, void* l) {
    __builtin_amdgcn_global_load_lds(
        (__attribute__((address_space(1))) const unsigned int*)g,
        (__attribute__((address_space(3))) unsigned int*)l, 16, 0, 0);
}

// ---------------- CSR build (by dst) ----------------
__global__ void hist_kernel(const int* __restrict__ dst, int* __restrict__ cnt, int E) {
    int e = blockIdx.x * blockDim.x + threadIdx.x;
    if (e < E) atomicAdd(&cnt[dst[e]], 1);
}

// single-block scan, wave-shfl based
__global__ __launch_bounds__(1024) void scan_kernel(const int* __restrict__ cnt,
                                                    int* __restrict__ row_off, int n) {
    __shared__ int wsum[16];
    __shared__ int carry_s;
    int tid = threadIdx.x;
    int lane = tid & 63, wid = tid >> 6;
    if (tid == 0) carry_s = 0;
    __syncthreads();
    for (int base = 0; base < n; base += 1024) {
        int i = base + tid;
        int x = (i < n) ? cnt[i] : 0;
        int v = x;
#pragma unroll
        for (int off = 1; off < 64; off <<= 1) {
            int y = __shfl_up(v, off);
            if (lane >= off) v += y;
        }
        if (lane == 63) wsum[wid] = v;
        __syncthreads();
        if (wid == 0) {
            int w = (lane < 16) ? wsum[lane] : 0;
#pragma unroll
            for (int off = 1; off < 16; off <<= 1) {
                int y = __shfl_up(w, off);
                if (lane >= off) w += y;
            }
            if (lane < 16) wsum[lane] = w;   // inclusive wave sums
        }
        __syncthreads();
        int wbase = (wid > 0) ? wsum[wid - 1] : 0;
        int carry = carry_s;
        if (i < n) row_off[i] = carry + wbase + v - x;   // exclusive
        int total = wsum[15];
        __syncthreads();
        if (tid == 0) carry_s = carry + total;
        __syncthreads();
    }
    if (tid == 0) row_off[n] = carry_s;
}

__global__ void scatter_kernel(const int* __restrict__ src, const int* __restrict__ dst,
                               const int* __restrict__ row_off, int* __restrict__ cur,
                               int* __restrict__ csr_src, int E) {
    int e = blockIdx.x * blockDim.x + threadIdx.x;
    if (e < E) {
        int d = dst[e];
        int pos = row_off[d] + atomicAdd(&cur[d], 1);
        csr_src[pos] = src[e];
    }
}

// ---------------- conversion kernels ----------------
__global__ void wqkv_cvt_kernel(const float* __restrict__ Wq, const float* __restrict__ Wk,
                                const float* __restrict__ Wv, _Float16* __restrict__ outw) {
    int i = blockIdx.x * blockDim.x + threadIdx.x;
    if (i >= N_LAYERS * QKVW * HID) return;
    int k = i & 255;
    int n = (i >> 8) % QKVW;
    int l = i / (QKVW * HID);
    int seg = n >> 8, nn = n & 255;
    const float* W = (seg == 0) ? Wq : (seg == 1) ? Wk : Wv;
    outw[i] = (_Float16)W[((size_t)l * HID + k) * HID + nn];
}

__global__ void win_cvt_kernel(const float* __restrict__ Win, _Float16* __restrict__ outw) {
    int i = blockIdx.x * blockDim.x + threadIdx.x;
    if (i >= HID * IN_DIM) return;
    int k = i & 127;
    int n = i >> 7;
    outw[i] = (_Float16)Win[(size_t)k * HID + n];
}

__global__ void wout_cvt_kernel(const float* __restrict__ Wout, _Float16* __restrict__ hi,
                                _Float16* __restrict__ lo) {
    int i = blockIdx.x * blockDim.x + threadIdx.x;
    if (i >= 128 * HID) return;
    int k = i & 255;
    int n = i >> 8;
    float v = (n < OUT_DIM) ? Wout[(size_t)k * OUT_DIM + n] : 0.f;
    _Float16 h = (_Float16)v;
    hi[i] = h;
    lo[i] = (_Float16)(v - (float)h);
}

__global__ void x_cvt_kernel(const float* __restrict__ X, _Float16* __restrict__ outx) {
    int i = blockIdx.x * blockDim.x + threadIdx.x;
    if (i >= MPAD * IN_DIM) return;
    int r = i >> 7;
    outx[i] = (_Float16)((r < N_NODES) ? X[i] : 0.f);
}

// ------- fp16 MFMA GEMM: tile 128x256, 3-buffer LDS, 2-ahead, XCD-clustered -------
// C[MPAD, Nc] = (A @ B^T + bias)*scale ; A [MPAD][K] f16, B^T [Nc][K] f16, C f16.
// block 256 (4 waves, 2x2), per-wave 64x128 out = acc[4][8] -> 32 MFMA/K-step/wave.
// NCOLT col-tiles of 256. 1-D grid: b=(q*NCOLT+j)*8+x -> row=q*8+x, col=j; all
// col-tiles of a row share (b&7) => same XCD => A-tile L2 reuse (round-7 win).
// STAGE = 6 global_load_lds (2 A + 4 B); 2 tiles ahead -> vmcnt(12)/(6)/(0).
template<int NT, int NCOLT>
__global__ __launch_bounds__(256, 2) void gemm16w(
        const _Float16* __restrict__ A, const _Float16* __restrict__ B,
        const float* __restrict__ bias0, const float* __restrict__ bias1,
        const float* __restrict__ bias2, float scale0,
        _Float16* __restrict__ C, int ldC) {
    __shared__ __align__(16) _Float16 lds[3][12288];   // 3 x [A(8KB) | B(16KB)] = 72KB
    const int K = NT * 32;

    const int bb = blockIdx.x;
    const int xx = bb & 7, tt = bb >> 3;
    const int qq = tt / NCOLT, jj = tt - qq * NCOLT;
    const int rowblk = qq * 8 + xx;
    if (rowblk >= NRB) return;
    const int row0 = rowblk * 128;
    const int n0   = jj * 256;

    const int tid  = threadIdx.x;
    const int lane = tid & 63;
    const int wave = tid >> 6;

    // staging: A tile [128 r][32 k] = 512 chunks (2/thread); B tile [256 r][32 k]
    // = 1024 chunks (4/thread). chunk p: row=p>>2, k-chunk=(p&3)^swz(row),
    // swz(r) = (r&3)^((r>>2)&3)  (involution, matched on read side)
    auto srcoff = [&](int p, int grow0) -> size_t {
        int row = p >> 2, cir = p & 3;
        int sw  = (row & 3) ^ ((row >> 2) & 3);
        int sc  = cir ^ sw;
        return (size_t)(grow0 + row) * K + sc * 8;   // element offset
    };
    const int pbase = wave * 64 + lane;
    const size_t offA0 = srcoff(pbase, row0), offA1 = srcoff(pbase + 256, row0);
    size_t offB[4];
#pragma unroll
    for (int u = 0; u < 4; ++u) offB[u] = srcoff(u * 256 + pbase, n0);
    const int dA0 = wave * 512, dA1 = 2048 + wave * 512;   // f16 offsets into A region

    const int mh = (wave >> 1) * 64;
    const int nh = (wave & 1) * 128;
    int aoff[4], boff[8];
#pragma unroll
    for (int f = 0; f < 4; ++f) {
        int ra = mh + f * 16 + (lane & 15);
        int ca = (lane >> 4) ^ ((ra & 3) ^ ((ra >> 2) & 3));
        aoff[f] = ra * 64 + ca * 16;   // bytes within A tile (row stride 64B)
    }
#pragma unroll
    for (int j = 0; j < 8; ++j) {
        int rb = nh + j * 16 + (lane & 15);
        int cb = (lane >> 4) ^ ((rb & 3) ^ ((rb >> 2) & 3));
        boff[j] = rb * 64 + cb * 16;   // bytes within B tile
    }

    f32x4 acc[4][8];
#pragma unroll
    for (int i = 0; i < 4; ++i)
#pragma unroll
        for (int j = 0; j < 8; ++j) acc[i][j] = {0.f, 0.f, 0.f, 0.f};

    auto STAGE = [&](int b, int t) {
        _Float16* LA = &lds[b][0];
        _Float16* LB = &lds[b][4096];
        const size_t k0 = (size_t)t * 32;
        gload_lds16(A + offA0 + k0, LA + dA0);
        gload_lds16(A + offA1 + k0, LA + dA1);
#pragma unroll
        for (int u = 0; u < 4; ++u)
            gload_lds16(B + offB[u] + k0, LB + u * 2048 + wave * 512);
    };

    STAGE(0, 0);
    STAGE(1, 1);   // NT >= 2 always
#pragma unroll
    for (int t = 0; t < NT; ++t) {
        if (t + 2 < NT) {
            STAGE((t + 2) % 3, t + 2);
            asm volatile("s_waitcnt vmcnt(12)" ::: "memory");  // tile t landed; t+1,t+2 in flight
        } else if (t + 1 < NT) {
            asm volatile("s_waitcnt vmcnt(6)" ::: "memory");
        } else {
            asm volatile("s_waitcnt vmcnt(0)" ::: "memory");
        }
        __builtin_amdgcn_s_barrier();
        const char* baseA = (const char*)&lds[t % 3][0];
        const char* baseB = (const char*)&lds[t % 3][4096];
        f16x8 af[4];
#pragma unroll
        for (int i = 0; i < 4; ++i)
            af[i] = *reinterpret_cast<const f16x8*>(baseA + aoff[i]);
#pragma unroll
        for (int j = 0; j < 8; ++j) {
            f16x8 bf = *reinterpret_cast<const f16x8*>(baseB + boff[j]);
#pragma unroll
            for (int i = 0; i < 4; ++i)
                acc[i][j] = __builtin_amdgcn_mfma_f32_16x16x32_f16(af[i], bf, acc[i][j], 0, 0, 0);
        }
        __builtin_amdgcn_s_barrier();   // buf (t%3) free for overwrite at t+3
    }

    const float* bias = (jj == 0) ? bias0 : (jj == 1) ? bias1 : bias2;
    const float scale = (jj == 0) ? scale0 : 1.f;
    const int fq = lane >> 4;
    const int fr = lane & 15;
#pragma unroll
    for (int i = 0; i < 4; ++i) {
#pragma unroll
        for (int j = 0; j < 8; ++j) {
#pragma unroll
            for (int r = 0; r < 4; ++r) {
                int m = row0 + mh + i * 16 + fq * 4 + r;
                int nc = nh + j * 16 + fr;          // 0..255 within segment
                float o = (acc[i][j][r] + bias[nc]) * scale;
                C[(size_t)m * ldC + n0 + nc] = (_Float16)o;
            }
        }
    }
}

// ---------------- out_proj: 2-term fp16 W split, fp32 out, guarded; 3-buffer ----------
__global__ __launch_bounds__(256) void gemm_out(
        const _Float16* __restrict__ A, const _Float16* __restrict__ Bh,
        const _Float16* __restrict__ Bl, const float* __restrict__ bias,
        float* __restrict__ C, int K) {
    __shared__ __align__(16) _Float16 lds[3][3 * 4096];   // 72KB

    const int tid  = threadIdx.x;
    const int lane = tid & 63;
    const int wave = tid >> 6;
    const int row0 = blockIdx.x * 128;

    const int p0 = wave * 64 + lane;
    const int p1 = p0 + 256;
    auto srcoff = [&](int p, int grow0) -> size_t {
        int row = p >> 2, cir = p & 3;
        int sw  = (row & 3) ^ ((row >> 2) & 3);
        int sc  = cir ^ sw;
        return (size_t)(grow0 + row) * K + sc * 8;
    };
    const size_t offA0 = srcoff(p0, row0), offA1 = srcoff(p1, row0);
    const size_t offB0 = srcoff(p0, 0),    offB1 = srcoff(p1, 0);
    const int d0 = wave * 512;
    const int d1 = 2048 + wave * 512;

    const int mh = (wave >> 1) * 64;
    const int nh = (wave & 1) * 64;
    int aoff[4], boff[4];
#pragma unroll
    for (int f = 0; f < 4; ++f) {
        int ra = mh + f * 16 + (lane & 15);
        int ca = (lane >> 4) ^ ((ra & 3) ^ ((ra >> 2) & 3));
        aoff[f] = ra * 64 + ca * 16;
        int rb = nh + f * 16 + (lane & 15);
        int cb = (lane >> 4) ^ ((rb & 3) ^ ((rb >> 2) & 3));
        boff[f] = rb * 64 + cb * 16;
    }

    f32x4 acc[4][4];
#pragma unroll
    for (int i = 0; i < 4; ++i)
#pragma unroll
        for (int j = 0; j < 4; ++j) acc[i][j] = {0.f, 0.f, 0.f, 0.f};

    auto STAGE = [&](int b, int t) {
        _Float16* LA  = &lds[b][0];
        _Float16* LBh = &lds[b][4096];
        _Float16* LBl = &lds[b][8192];
        const size_t k0 = (size_t)t * 32;
        gload_lds16(A  + offA0 + k0, LA  + d0);
        gload_lds16(A  + offA1 + k0, LA  + d1);
        gload_lds16(Bh + offB0 + k0, LBh + d0);
        gload_lds16(Bh + offB1 + k0, LBh + d1);
        gload_lds16(Bl + offB0 + k0, LBl + d0);
        gload_lds16(Bl + offB1 + k0, LBl + d1);
    };

    STAGE(0, 0);
    STAGE(1, 1);
#pragma unroll
    for (int t = 0; t < 8; ++t) {
        if (t + 2 < 8) {
            STAGE((t + 2) % 3, t + 2);
            asm volatile("s_waitcnt vmcnt(12)" ::: "memory");
        } else if (t + 1 < 8) {
            asm volatile("s_waitcnt vmcnt(6)" ::: "memory");
        } else {
            asm volatile("s_waitcnt vmcnt(0)" ::: "memory");
        }
        __builtin_amdgcn_s_barrier();
        const char* baseA  = (const char*)&lds[t % 3][0];
        const char* baseBh = (const char*)&lds[t % 3][4096];
        const char* baseBl = (const char*)&lds[t % 3][8192];
        f16x8 af[4];
#pragma unroll
        for (int i = 0; i < 4; ++i)
            af[i] = *reinterpret_cast<const f16x8*>(baseA + aoff[i]);
#pragma unroll
        for (int j = 0; j < 4; ++j) {
            f16x8 bh = *reinterpret_cast<const f16x8*>(baseBh + boff[j]);
            f16x8 bl = *reinterpret_cast<const f16x8*>(baseBl + boff[j]);
#pragma unroll
            for (int i = 0; i < 4; ++i) {
                acc[i][j] = __builtin_amdgcn_mfma_f32_16x16x32_f16(af[i], bh, acc[i][j], 0, 0, 0);
                acc[i][j] = __builtin_amdgcn_mfma_f32_16x16x32_f16(af[i], bl, acc[i][j], 0, 0, 0);
            }
        }
        __builtin_amdgcn_s_barrier();
    }

    const int fq = lane >> 4;
    const int fr = lane & 15;
#pragma unroll
    for (int i = 0; i < 4; ++i) {
#pragma unroll
        for (int j = 0; j < 4; ++j) {
#pragma unroll
            for (int r = 0; r < 4; ++r) {
                int m = row0 + mh + i * 16 + fq * 4 + r;
                int n = nh + j * 16 + fr;
                if (m < N_NODES && n < OUT_DIM)
                    C[(size_t)m * OUT_DIM + n] = acc[i][j][r] + bias[n];
            }
        }
    }
}

// ---------------- fused SDDMM + segment-softmax + SpMM (round-6 form, best) ----------
// one wave per dst node; lane -> head = lane>>3, dims lane*4 .. +4; 4-edge unroll.
// qkv rows: [q(256) | k(256) | v(256)] fp16
__global__ __launch_bounds__(256) void attn_kernel(
        const _Float16* __restrict__ qkv, const int* __restrict__ row_off,
        const int* __restrict__ csr_src, _Float16* __restrict__ h_out, int n) {
    int wave = threadIdx.x >> 6;
    int lane = threadIdx.x & 63;
    int node = blockIdx.x * 4 + wave;
    if (node >= n) return;
    const int loff = lane * 4;
    float4 qv;
    {
        float2 raw = *reinterpret_cast<const float2*>(&qkv[(size_t)node * QKVW + loff]);
        const __half2* h2 = reinterpret_cast<const __half2*>(&raw);
        float2 a = __half22float2(h2[0]), b = __half22float2(h2[1]);
        qv = make_float4(a.x, a.y, b.x, b.y);
    }
    float4 acc = make_float4(0.f, 0.f, 0.f, 0.f);
    float m = -INFINITY, s = 0.f;
    int beg = row_off[node], end = row_off[node + 1];
    int idx = beg;

#define LOAD_KV(slot, sn)                                                                 \
    float2 kr##slot, vr##slot;                                                            \
    {                                                                                     \
        const _Float16* base = qkv + (size_t)(sn) * QKVW;                                 \
        kr##slot = *reinterpret_cast<const float2*>(base + HID + loff);                   \
        vr##slot = *reinterpret_cast<const float2*>(base + 2 * HID + loff);               \
    }

#define DOT(slot, dvar)                                                                   \
    float dvar;                                                                           \
    {                                                                                     \
        const __half2* kh = reinterpret_cast<const __half2*>(&kr##slot);                  \
        float2 k01 = __half22float2(kh[0]), k23 = __half22float2(kh[1]);                  \
        dvar = qv.x * k01.x + qv.y * k01.y + qv.z * k23.x + qv.w * k23.y;                 \
        dvar += __shfl_xor(dvar, 1);                                                      \
        dvar += __shfl_xor(dvar, 2);                                                      \
        dvar += __shfl_xor(dvar, 4);                                                      \
    }

#define VADD(slot, p)                                                                     \
    {                                                                                     \
        const __half2* vh = reinterpret_cast<const __half2*>(&vr##slot);                  \
        float2 v01 = __half22float2(vh[0]), v23 = __half22float2(vh[1]);                  \
        acc.x = fmaf(p, v01.x, acc.x);                                                    \
        acc.y = fmaf(p, v01.y, acc.y);                                                    \
        acc.z = fmaf(p, v23.x, acc.z);                                                    \
        acc.w = fmaf(p, v23.y, acc.w);                                                    \
    }

    for (; idx + 3 < end; idx += 4) {
        int s0 = csr_src[idx], s1 = csr_src[idx + 1];
        int s2 = csr_src[idx + 2], s3 = csr_src[idx + 3];
        LOAD_KV(0, s0) LOAD_KV(1, s1) LOAD_KV(2, s2) LOAD_KV(3, s3)
        DOT(0, e0) DOT(1, e1) DOT(2, e2) DOT(3, e3)
        float mn = fmaxf(fmaxf(fmaxf(m, e0), fmaxf(e1, e2)), e3);
        float c  = __expf(m - mn);
        float p0 = __expf(e0 - mn), p1 = __expf(e1 - mn);
        float p2 = __expf(e2 - mn), p3 = __expf(e3 - mn);
        s = fmaf(s, c, (p0 + p1) + (p2 + p3));
        acc.x *= c; acc.y *= c; acc.z *= c; acc.w *= c;
        VADD(0, p0) VADD(1, p1) VADD(2, p2) VADD(3, p3)
        m = mn;
    }
    for (; idx < end; ++idx) {
        int s0 = csr_src[idx];
        LOAD_KV(0, s0)
        DOT(0, e0)
        float mn = fmaxf(m, e0);
        float c = __expf(m - mn);
        float p0 = __expf(e0 - mn);
        s = fmaf(s, c, p0);
        acc.x *= c; acc.y *= c; acc.z *= c; acc.w *= c;
        VADD(0, p0)
        m = mn;
    }
#undef LOAD_KV
#undef DOT
#undef VADD

    float inv = (s > 0.f) ? 1.f / s : 0.f;
    __half2 o01 = __floats2half2_rn(acc.x * inv, acc.y * inv);
    __half2 o23 = __floats2half2_rn(acc.z * inv, acc.w * inv);
    union { __half2 h2[2]; float2 f2; } u;
    u.h2[0] = o01; u.h2[1] = o23;
    *reinterpret_cast<float2*>(&h_out[(size_t)node * HID + loff]) = u.f2;
}

extern "C" void kernel_launch(void* const* d_in, const int* in_sizes, int n_in,
                              void* d_out, int out_size, void* d_ws, size_t ws_size,
                              hipStream_t stream) {
    const float* X    = (const float*)d_in[0];
    const int*   src  = (const int*)d_in[1];
    const int*   dst  = (const int*)d_in[2];
    const float* Win  = (const float*)d_in[3];
    const float* bin_ = (const float*)d_in[4];
    const float* Wq   = (const float*)d_in[5];
    const float* Wk   = (const float*)d_in[6];
    const float* Wv   = (const float*)d_in[7];
    const float* bq   = (const float*)d_in[8];
    const float* bk   = (const float*)d_in[9];
    const float* bv   = (const float*)d_in[10];
    const float* Wout = (const float*)d_in[11];
    const float* bout = (const float*)d_in[12];
    float* out = (float*)d_out;

    char* ws = (char*)d_ws;
    size_t off = 0;
    auto alloc = [&](size_t bytes) -> void* {
        void* p = ws + off;
        off = (off + bytes + 255) & ~(size_t)255;
        return p;
    };
    _Float16* qkv   = (_Float16*)alloc((size_t)MPAD * QKVW * 2);
    _Float16* h     = (_Float16*)alloc((size_t)MPAD * HID * 2);
    _Float16* Xf    = (_Float16*)alloc((size_t)MPAD * IN_DIM * 2);
    _Float16* Wqkvt = (_Float16*)alloc((size_t)N_LAYERS * QKVW * HID * 2);
    _Float16* Wint  = (_Float16*)alloc((size_t)HID * IN_DIM * 2);
    _Float16* Wot_h = (_Float16*)alloc((size_t)128 * HID * 2);
    _Float16* Wot_l = (_Float16*)alloc((size_t)128 * HID * 2);
    int* cnt     = (int*)alloc(sizeof(int) * 2 * N_NODES);   // [hist | scatter-cursor]
    int* row_off = (int*)alloc(sizeof(int) * (N_NODES + 1));
    int* csr_src = (int*)alloc(sizeof(int) * N_EDGES);

    // CSR build (one memset covers both counter arrays)
    hipMemsetAsync(cnt, 0, sizeof(int) * 2 * N_NODES, stream);
    hist_kernel<<<(N_EDGES + 255) / 256, 256, 0, stream>>>(dst, cnt, N_EDGES);
    scan_kernel<<<1, 1024, 0, stream>>>(cnt, row_off, N_NODES);
    scatter_kernel<<<(N_EDGES + 255) / 256, 256, 0, stream>>>(src, dst, row_off,
                                                              cnt + N_NODES, csr_src, N_EDGES);

    // conversions
    {
        int t1 = N_LAYERS * QKVW * HID;
        wqkv_cvt_kernel<<<(t1 + 255) / 256, 256, 0, stream>>>(Wq, Wk, Wv, Wqkvt);
        int t2 = HID * IN_DIM;
        win_cvt_kernel<<<(t2 + 255) / 256, 256, 0, stream>>>(Win, Wint);
        int t3 = 128 * HID;
        wout_cvt_kernel<<<(t3 + 255) / 256, 256, 0, stream>>>(Wout, Wot_h, Wot_l);
        int t4 = MPAD * IN_DIM;
        x_cvt_kernel<<<(t4 + 255) / 256, 256, 0, stream>>>(X, Xf);
    }

    dim3 blk(256);
    const int NQG = (NRB + 7) / 8;   // 49 row-groups of 8
    // in_proj: h = X @ Win + bin  (fp16 out, ldC=256), K=128 -> NT=4, 1 col-tile of 256
    gemm16w<4, 1><<<dim3(NQG * 1 * 8), blk, 0, stream>>>(
        Xf, Wint, bin_, bin_, bin_, 1.f, h, HID);

    for (int l = 0; l < N_LAYERS; ++l) {
        const _Float16* Bl = Wqkvt + (size_t)l * QKVW * HID;
        // fused QKV: K=256 -> NT=8, 3 col-tiles of 256
        gemm16w<8, 3><<<dim3(NQG * 3 * 8), blk, 0, stream>>>(
            h, Bl, bq + l * HID, bk + l * HID, bv + l * HID, SCALING, qkv, QKVW);
        attn_kernel<<<(N_NODES + 3) / 4, blk, 0, stream>>>(
            qkv, row_off, csr_src, h, N_NODES);
    }
    // out_proj
    gemm_out<<<dim3(NRB), blk, 0, stream>>>(
        h, Wot_h, Wot_l, bout, out, HID);
}